// Round 1
// baseline (178.883 us; speedup 1.0000x reference)
//
#include <hip/hip_runtime.h>

#define ALPHA 0.8f
#define SPB 64      // samples per block
#define LDW 68      // k-row stride of staged tiles (68*4B = 272B: 16B-aligned rows, 2-way banks)
#define IVW 129     // imu/vis LDS row stride (odd -> 2-way bank conflict max)

// ---------------- prep kernels: collapse r1+r2 into G[144][32], c[32] ----------------
// h[r] = b_r1[r] + sum_k imu[k]*CA[r][k] + sum_k vis[k]*CV[r][k]
//        + 0.8*sum_j ha[j]*RSa[r][j] + 0.2*sum_j hv[j]*RSv[r][j]
// out[o] = sum_r h[r]*W_r2[o][r] + b_r2[o]  ==>  out = X[144] * G + c
__global__ void prepA(const float* __restrict__ Wr1, float* __restrict__ M) {
    int idx = blockIdx.x * 256 + threadIdx.x;
    if (idx >= 144 * 128) return;
    int x = idx >> 7;
    int r = idx & 127;
    const float* row = Wr1 + (size_t)r * 1024;
    float s = 0.f;
    if (x < 64) {
        #pragma unroll
        for (int j = 0; j < 8; ++j) s += row[j * 128 + x];
    } else if (x < 128) {
        #pragma unroll
        for (int j = 0; j < 8; ++j) s += row[j * 128 + 64 + (x - 64)];
    } else if (x < 136) {
        int j = x - 128;
        for (int k = 0; k < 64; ++k) s += row[j * 128 + k];
    } else {
        int j = x - 136;
        for (int k = 0; k < 64; ++k) s += row[j * 128 + 64 + k];
    }
    M[x * 128 + r] = s;
}

__global__ void prepB(const float* __restrict__ M, const float* __restrict__ Wr2,
                      const float* __restrict__ br1, const float* __restrict__ br2,
                      float* __restrict__ G, float* __restrict__ c) {
    int idx = blockIdx.x * 256 + threadIdx.x;
    if (idx < 144 * 32) {
        int x = idx >> 5, o = idx & 31;
        const float* m = M + x * 128;
        const float* w = Wr2 + o * 128;
        float s = 0.f;
        for (int r = 0; r < 128; ++r) s = fmaf(m[r], w[r], s);
        G[x * 32 + o] = s;
    } else if (idx < 144 * 32 + 32) {
        int o = idx - 144 * 32;
        const float* w = Wr2 + o * 128;
        float s = br2[o];
        for (int r = 0; r < 128; ++r) s = fmaf(br1[r], w[r], s);
        c[o] = s;
    }
}

// ---------------- main kernel ----------------
template <int KLEN, int K>
__device__ __forceinline__ void stageT(const float* __restrict__ src, float* __restrict__ dst,
                                       int row0, int kc, int t) {
    constexpr int F4 = KLEN / 4;
    constexpr int N4 = 64 * F4;
    for (int i = t; i < N4; i += 256) {
        int row = i / F4;            // 0..63 (sample or output row)
        int c4 = (i % F4) * 4;       // k offset within chunk
        const float4 v = *(const float4*)(src + (size_t)(row0 + row) * K + kc + c4);
        dst[(c4 + 0) * LDW + row] = v.x;
        dst[(c4 + 1) * LDW + row] = v.y;
        dst[(c4 + 2) * LDW + row] = v.z;
        dst[(c4 + 3) * LDW + row] = v.w;
    }
}

template <int KLEN>
__device__ __forceinline__ void macT(const float* __restrict__ sAT, const float* __restrict__ sWT,
                                     int ss, int so, float acc[4][4]) {
    #pragma unroll 8
    for (int k = 0; k < KLEN; ++k) {
        const float4 a4 = *(const float4*)(sAT + k * LDW + ss);
        const float4 w4 = *(const float4*)(sWT + k * LDW + so);
        const float a[4] = {a4.x, a4.y, a4.z, a4.w};
        const float w[4] = {w4.x, w4.y, w4.z, w4.w};
        #pragma unroll
        for (int si = 0; si < 4; ++si)
            #pragma unroll
            for (int oi = 0; oi < 4; ++oi)
                acc[si][oi] = fmaf(a[si], w[oi], acc[si][oi]);
    }
}

template <int K>
__device__ void enc(const float* __restrict__ X, const float* __restrict__ W,
                    const float* __restrict__ bias,
                    float* sAT, float* sWT, float* sIV, int colbase, int s0, int t) {
    const int so = (t & 15) * 4;   // output base 0..60
    const int ss = (t >> 4) * 4;   // sample base 0..60
    float acc[4][4] = {{0.f,0.f,0.f,0.f},{0.f,0.f,0.f,0.f},{0.f,0.f,0.f,0.f},{0.f,0.f,0.f,0.f}};
    constexpr int KMAIN = (K / 32) * 32;
    for (int kc = 0; kc < KMAIN; kc += 32) {
        stageT<32, K>(X, sAT, s0, kc, t);
        stageT<32, K>(W, sWT, 0, kc, t);
        __syncthreads();
        macT<32>(sAT, sWT, ss, so, acc);
        __syncthreads();
    }
    if constexpr ((K % 32) != 0) {
        constexpr int KT = K % 32;
        stageT<KT, K>(X, sAT, s0, KMAIN, t);
        stageT<KT, K>(W, sWT, 0, KMAIN, t);
        __syncthreads();
        macT<KT>(sAT, sWT, ss, so, acc);
        __syncthreads();
    }
    #pragma unroll
    for (int si = 0; si < 4; ++si)
        #pragma unroll
        for (int oi = 0; oi < 4; ++oi)
            sIV[(ss + si) * IVW + colbase + so + oi] = acc[si][oi] + bias[so + oi];
}

__global__ __launch_bounds__(256)
void mica_main(const float* __restrict__ f1, const float* __restrict__ f2,
               const float* __restrict__ We1, const float* __restrict__ be1,
               const float* __restrict__ We2, const float* __restrict__ be2,
               const float* __restrict__ Waffa, const float* __restrict__ Waffv,
               const float* __restrict__ Wa, const float* __restrict__ Wv,
               const float* __restrict__ Wca, const float* __restrict__ Wcv,
               const float* __restrict__ Wha, const float* __restrict__ Whv,
               const float* __restrict__ G, const float* __restrict__ cvec,
               float* __restrict__ out) {
    __shared__ float sIV[SPB * IVW];          // [64 samples][imu(64) | vis(64)]
    __shared__ float scratch[2 * 32 * LDW];   // enc tiles; reused as reduction buffers
    float* sAT = scratch;
    float* sWT = scratch + 32 * LDW;
    const int t = threadIdx.x;
    const int s0 = blockIdx.x * SPB;

    // ---- phase 1: encoders into LDS ----
    enc<768>(f1, We1, be1, sAT, sWT, sIV, 0, s0, t);
    enc<600>(f2, We2, be2, sAT, sWT, sIV, 64, s0, t);
    __syncthreads();

    // ---- phase 2: per-sample tail; lane s = sample, q = output-quarter ----
    const int s = t & 63;
    const int q = t >> 6;
    const float* iv = sIV + s * IVW;
    float* red = scratch;

    // step 3: moments Sii, Siv, Svv (4-way split over k)
    float sii = 0.f, siv = 0.f, svv = 0.f;
    #pragma unroll
    for (int kk = 0; kk < 16; ++kk) {
        int k = q * 16 + kk;
        float a = iv[k], b = iv[64 + k];
        sii = fmaf(a, a, sii);
        siv = fmaf(a, b, siv);
        svv = fmaf(b, b, svv);
    }
    red[(q * 3 + 0) * 64 + s] = sii;
    red[(q * 3 + 1) * 64 + s] = siv;
    red[(q * 3 + 2) * 64 + s] = svv;
    __syncthreads();
    sii = red[0 * 64 + s] + red[3 * 64 + s] + red[6 * 64 + s] + red[9 * 64 + s];
    siv = red[1 * 64 + s] + red[4 * 64 + s] + red[7 * 64 + s] + red[10 * 64 + s];
    svv = red[2 * 64 + s] + red[5 * 64 + s] + red[8 * 64 + s] + red[11 * 64 + s];

    // step 4: attention gates (scale = 1/sqrt(64) = 0.125)
    float ia[8], va[8];
    #pragma unroll
    for (int j = 0; j < 8; ++j) {
        ia[j] = tanhf((sii * Waffa[j * 2 + 0] + siv * Waffa[j * 2 + 1]) * 0.125f);
        va[j] = tanhf((siv * Waffv[j * 2 + 0] + svv * Waffv[j * 2 + 1]) * 0.125f);
    }

    // steps 5-6: H_a, H_v (this thread owns m = q*8 .. q*8+7)
    float Ha[8], Hv[8];
    #pragma unroll
    for (int mi = 0; mi < 8; ++mi) {
        int m = q * 8 + mi;
        float sa = 0.f, sv = 0.f;
        #pragma unroll
        for (int j = 0; j < 8; ++j) {
            sa = fmaf(ia[j], Wca[m * 8 + j], sa);
            sv = fmaf(va[j], Wcv[m * 8 + j], sv);
        }
        Ha[mi] = sa; Hv[mi] = sv;
    }
    for (int k = 0; k < 64; ++k) {
        float a = iv[k], b = iv[64 + k];
        #pragma unroll
        for (int mi = 0; mi < 8; ++mi) {
            int m = q * 8 + mi;
            Ha[mi] = fmaf(a, Wa[m * 64 + k], Ha[mi]);
            Hv[mi] = fmaf(b, Wv[m * 64 + k], Hv[mi]);
        }
    }
    #pragma unroll
    for (int mi = 0; mi < 8; ++mi) {
        Ha[mi] = fmaxf(ALPHA * Ha[mi], 0.f);
        Hv[mi] = fmaxf((1.f - ALPHA) * Hv[mi], 0.f);
    }

    __syncthreads();   // protect red reuse (step-3 reads done before step-7 writes)

    // step 7: ha/hv partials over this thread's m-range
    #pragma unroll
    for (int j = 0; j < 8; ++j) {
        float hap = 0.f, hvp = 0.f;
        #pragma unroll
        for (int mi = 0; mi < 8; ++mi) {
            hap = fmaf(Ha[mi], Wha[j * 32 + q * 8 + mi], hap);
            hvp = fmaf(Hv[mi], Whv[j * 32 + q * 8 + mi], hvp);
        }
        red[(q * 16 + j) * 64 + s] = hap;
        red[(q * 16 + 8 + j) * 64 + s] = hvp;
    }
    __syncthreads();
    float ha[8], hv[8];
    #pragma unroll
    for (int j = 0; j < 8; ++j) {
        ha[j] = red[(0 * 16 + j) * 64 + s] + red[(1 * 16 + j) * 64 + s]
              + red[(2 * 16 + j) * 64 + s] + red[(3 * 16 + j) * 64 + s];
        hv[j] = red[(0 * 16 + 8 + j) * 64 + s] + red[(1 * 16 + 8 + j) * 64 + s]
              + red[(2 * 16 + 8 + j) * 64 + s] + red[(3 * 16 + 8 + j) * 64 + s];
    }

    // step 9: out = X[144] * G + c  (this thread: o = q*8 .. q*8+7)
    float o8[8];
    #pragma unroll
    for (int oi = 0; oi < 8; ++oi) o8[oi] = cvec[q * 8 + oi];
    for (int k = 0; k < 128; ++k) {
        float a = iv[k];   // k<64: imu, k>=64: vis (G rows ordered to match)
        #pragma unroll
        for (int oi = 0; oi < 8; ++oi)
            o8[oi] = fmaf(a, G[k * 32 + q * 8 + oi], o8[oi]);
    }
    #pragma unroll
    for (int j = 0; j < 8; ++j) {
        float aj = ALPHA * ha[j];
        float vj = (1.f - ALPHA) * hv[j];
        #pragma unroll
        for (int oi = 0; oi < 8; ++oi) {
            o8[oi] = fmaf(aj, G[(128 + j) * 32 + q * 8 + oi], o8[oi]);
            o8[oi] = fmaf(vj, G[(136 + j) * 32 + q * 8 + oi], o8[oi]);
        }
    }
    float4 v0 = {o8[0], o8[1], o8[2], o8[3]};
    float4 v1 = {o8[4], o8[5], o8[6], o8[7]};
    float* op = out + (size_t)(s0 + s) * 32 + q * 8;
    *(float4*)op = v0;
    *((float4*)op + 1) = v1;
}

extern "C" void kernel_launch(void* const* d_in, const int* in_sizes, int n_in,
                              void* d_out, int out_size, void* d_ws, size_t ws_size,
                              hipStream_t stream) {
    const float* f1    = (const float*)d_in[0];
    const float* f2    = (const float*)d_in[1];
    const float* We1   = (const float*)d_in[2];
    const float* be1   = (const float*)d_in[3];
    const float* We2   = (const float*)d_in[4];
    const float* be2   = (const float*)d_in[5];
    const float* Waffa = (const float*)d_in[6];
    const float* Waffv = (const float*)d_in[7];
    const float* Wa    = (const float*)d_in[8];
    const float* Wv    = (const float*)d_in[9];
    const float* Wca   = (const float*)d_in[10];
    const float* Wcv   = (const float*)d_in[11];
    const float* Wha   = (const float*)d_in[12];
    const float* Whv   = (const float*)d_in[13];
    const float* Wr1   = (const float*)d_in[14];
    const float* br1   = (const float*)d_in[15];
    const float* Wr2   = (const float*)d_in[16];
    const float* br2   = (const float*)d_in[17];
    float* outp = (float*)d_out;

    const int Btot = in_sizes[0] / 768;

    float* M = (float*)d_ws;            // 144*128
    float* G = M + 144 * 128;           // 144*32
    float* c = G + 144 * 32;            // 32   (total ~92 KB of d_ws)

    prepA<<<(144 * 128 + 255) / 256, 256, 0, stream>>>(Wr1, M);
    prepB<<<(144 * 32 + 32 + 255) / 256, 256, 0, stream>>>(M, Wr2, br1, br2, G, c);
    mica_main<<<Btot / SPB, 256, 0, stream>>>(f1, f2, We1, be1, We2, be2,
                                              Waffa, Waffv, Wa, Wv, Wca, Wcv, Wha, Whv,
                                              G, c, outp);
}

// Round 2
// 98.354 us; speedup vs baseline: 1.8188x; 1.8188x over previous
//
#include <hip/hip_runtime.h>
#include <hip/hip_bf16.h>

#define ALPHA 0.8f
#define SPB 64      // samples per block
#define IVW 132     // imu/vis LDS row stride (float4-aligned; 4-way max on vec reads)

typedef __attribute__((ext_vector_type(8))) short bf16x8;
typedef __attribute__((ext_vector_type(8))) unsigned short ushort8;
typedef __attribute__((ext_vector_type(4))) float f32x4;

__device__ __host__ __forceinline__ unsigned short bfu(float x) {
    __hip_bfloat16 h = __float2bfloat16(x);   // RNE
    return __builtin_bit_cast(unsigned short, h);
}

// ---------------- prep kernels ----------------
// collapse r1+r2 into G[144][32], c[32]  (verified in R0)
__global__ void prepA(const float* __restrict__ Wr1, float* __restrict__ M) {
    int idx = blockIdx.x * 256 + threadIdx.x;
    if (idx >= 144 * 128) return;
    int x = idx >> 7;
    int r = idx & 127;
    const float* row = Wr1 + (size_t)r * 1024;
    float s = 0.f;
    if (x < 64) {
        #pragma unroll
        for (int j = 0; j < 8; ++j) s += row[j * 128 + x];
    } else if (x < 128) {
        #pragma unroll
        for (int j = 0; j < 8; ++j) s += row[j * 128 + 64 + (x - 64)];
    } else if (x < 136) {
        int j = x - 128;
        for (int k = 0; k < 64; ++k) s += row[j * 128 + k];
    } else {
        int j = x - 136;
        for (int k = 0; k < 64; ++k) s += row[j * 128 + 64 + k];
    }
    M[x * 128 + r] = s;
}

__global__ void prepB(const float* __restrict__ M, const float* __restrict__ Wr2,
                      const float* __restrict__ br1, const float* __restrict__ br2,
                      float* __restrict__ G, float* __restrict__ c) {
    int idx = blockIdx.x * 256 + threadIdx.x;
    if (idx < 144 * 32) {
        int x = idx >> 5, o = idx & 31;
        const float* m = M + x * 128;
        const float* w = Wr2 + o * 128;
        float s = 0.f;
        for (int r = 0; r < 128; ++r) s = fmaf(m[r], w[r], s);
        G[x * 32 + o] = s;
    } else if (idx < 144 * 32 + 32) {
        int o = idx - 144 * 32;
        const float* w = Wr2 + o * 128;
        float s = br2[o];
        for (int r = 0; r < 128; ++r) s = fmaf(br1[r], w[r], s);
        c[o] = s;
    }
}

// convert encoder weights to bf16; enc2 padded [64][640] with zeros past k=600
__global__ void prepW(const float* __restrict__ We1, const float* __restrict__ We2,
                      unsigned short* __restrict__ Wb1, unsigned short* __restrict__ Wb2) {
    int i = blockIdx.x * 256 + threadIdx.x;
    if (i < 64 * 768) Wb1[i] = bfu(We1[i]);
    if (i < 64 * 640) {
        int r = i / 640, k = i - r * 640;
        Wb2[i] = (k < 600) ? bfu(We2[r * 600 + k]) : (unsigned short)0;
    }
}

// ---------------- main kernel: 512 threads = 8 waves, 64 samples/block ----------------
// Encoder GEMM via mfma_f32_16x16x32_bf16.
// LDS tiles sA[64][64]bf16, sW[64][64]bf16, 16B-chunk XOR swizzle: phys_chunk = c ^ (row&7).
// Wave w: m-rows 16*(w&3).. , n-cols 32*(w>>2)..  (2 MFMA accs per K-step).
template <int ROWLEN, int KLEN, int KPAD>
__device__ __forceinline__ void encMF(const float* __restrict__ X, const unsigned short* __restrict__ Wb,
                                      const float* __restrict__ bias,
                                      short* sA, short* sW, float* sIV,
                                      int colbase, int s0, int t) {
    const int w = t >> 6, l = t & 63;
    const int mb = 16 * (w & 3), nb = 32 * (w >> 2);
    const int r16 = l & 15, kg = l >> 4;
    const int sr = t >> 3, sc = t & 7;            // staging: row 0..63, chunk 0..7
    const int sphys = sc ^ (sr & 7);
    const float* xrow = X + (size_t)(s0 + sr) * ROWLEN;
    const unsigned short* wrow = Wb + sr * KPAD;

    f32x4 acc0 = {0.f, 0.f, 0.f, 0.f}, acc1 = {0.f, 0.f, 0.f, 0.f};

    // precompute fragment read offsets (bytes)
    const int arow = mb + r16;
    const int n0 = nb + r16, n1 = nb + 16 + r16;

    for (int kc = 0; kc < KPAD; kc += 64) {
        __syncthreads();   // prev chunk's frag reads done before overwrite
        const int k0 = kc + sc * 8;
        ushort8 pa;
        #pragma unroll
        for (int j = 0; j < 8; ++j) pa[j] = 0;
        if (KLEN == KPAD || k0 < KLEN) {
            const float4 u = *(const float4*)(xrow + k0);
            const float4 v = *(const float4*)(xrow + k0 + 4);
            pa[0] = bfu(u.x); pa[1] = bfu(u.y); pa[2] = bfu(u.z); pa[3] = bfu(u.w);
            pa[4] = bfu(v.x); pa[5] = bfu(v.y); pa[6] = bfu(v.z); pa[7] = bfu(v.w);
        }
        *(ushort8*)((char*)sA + sr * 128 + sphys * 16) = pa;
        *(ushort8*)((char*)sW + sr * 128 + sphys * 16) = *(const ushort8*)(wrow + k0);
        __syncthreads();
        #pragma unroll
        for (int ks = 0; ks < 2; ++ks) {
            const int ca = kg + 4 * ks;
            const bf16x8 af = *(const bf16x8*)((const char*)sA + arow * 128 + ((ca ^ (arow & 7)) * 16));
            const bf16x8 b0 = *(const bf16x8*)((const char*)sW + n0 * 128 + ((ca ^ (n0 & 7)) * 16));
            const bf16x8 b1 = *(const bf16x8*)((const char*)sW + n1 * 128 + ((ca ^ (n1 & 7)) * 16));
            acc0 = __builtin_amdgcn_mfma_f32_16x16x32_bf16(af, b0, acc0, 0, 0, 0);
            acc1 = __builtin_amdgcn_mfma_f32_16x16x32_bf16(af, b1, acc1, 0, 0, 0);
        }
    }
    // C/D layout: col = lane&15, row = 4*(lane>>4) + reg   [guide §3, m89-verified]
    const int rr = 4 * (l >> 4);
    #pragma unroll
    for (int reg = 0; reg < 4; ++reg) {
        const int row = mb + rr + reg;
        sIV[row * IVW + colbase + nb + r16]      = acc0[reg] + bias[nb + r16];
        sIV[row * IVW + colbase + nb + 16 + r16] = acc1[reg] + bias[nb + 16 + r16];
    }
}

__global__ __launch_bounds__(512, 4)
void mica_main(const float* __restrict__ f1, const float* __restrict__ f2,
               const unsigned short* __restrict__ Wb1, const unsigned short* __restrict__ Wb2,
               const float* __restrict__ be1, const float* __restrict__ be2,
               const float* __restrict__ Waffa, const float* __restrict__ Waffv,
               const float* __restrict__ Wa, const float* __restrict__ Wv,
               const float* __restrict__ Wca, const float* __restrict__ Wcv,
               const float* __restrict__ Wha, const float* __restrict__ Whv,
               const float* __restrict__ G, const float* __restrict__ cvec,
               float* __restrict__ out) {
    __shared__ float sIV[SPB * IVW];     // 33.8 KB  [64 samples][imu(64)|vis(64)]
    __shared__ float scratch[8192];      // 32 KB: staging tiles (16 KB) / reduction buf
    short* sA = (short*)scratch;
    short* sW = (short*)scratch + 4096;
    const int t = threadIdx.x;
    const int s0 = blockIdx.x * SPB;

    // ---- phase 1: MFMA encoders into sIV ----
    encMF<768, 768, 768>(f1, Wb1, be1, sA, sW, sIV, 0, s0, t);
    encMF<600, 600, 640>(f2, Wb2, be2, sA, sW, sIV, 64, s0, t);
    __syncthreads();

    // ---- phase 2: per-sample tail; s = sample, q = wave = work-slice ----
    const int s = t & 63;
    const int q = t >> 6;                 // 0..7, wave-uniform
    const float* iv = sIV + s * IVW;
    float* red = scratch;

    // step 3: moments Sii, Siv, Svv (8-way split over k)
    float sii, siv, svv;
    {
        const f32x4 a0 = *(const f32x4*)(iv + q * 8);
        const f32x4 a1 = *(const f32x4*)(iv + q * 8 + 4);
        const f32x4 b0 = *(const f32x4*)(iv + 64 + q * 8);
        const f32x4 b1 = *(const f32x4*)(iv + 64 + q * 8 + 4);
        sii = a0[0]*a0[0]; siv = a0[0]*b0[0]; svv = b0[0]*b0[0];
        #pragma unroll
        for (int j = 1; j < 4; ++j) {
            sii = fmaf(a0[j], a0[j], sii); siv = fmaf(a0[j], b0[j], siv); svv = fmaf(b0[j], b0[j], svv);
        }
        #pragma unroll
        for (int j = 0; j < 4; ++j) {
            sii = fmaf(a1[j], a1[j], sii); siv = fmaf(a1[j], b1[j], siv); svv = fmaf(b1[j], b1[j], svv);
        }
    }
    red[(q * 3 + 0) * 64 + s] = sii;
    red[(q * 3 + 1) * 64 + s] = siv;
    red[(q * 3 + 2) * 64 + s] = svv;
    __syncthreads();
    sii = 0.f; siv = 0.f; svv = 0.f;
    #pragma unroll
    for (int g = 0; g < 8; ++g) {
        sii += red[(g * 3 + 0) * 64 + s];
        siv += red[(g * 3 + 1) * 64 + s];
        svv += red[(g * 3 + 2) * 64 + s];
    }

    // step 4: attention gates (scale = 1/8)
    float ia[8], va[8];
    #pragma unroll
    for (int j = 0; j < 8; ++j) {
        ia[j] = tanhf((sii * Waffa[j * 2 + 0] + siv * Waffa[j * 2 + 1]) * 0.125f);
        va[j] = tanhf((siv * Waffv[j * 2 + 0] + svv * Waffv[j * 2 + 1]) * 0.125f);
    }

    // steps 5-6: H_a, H_v — this thread owns m = q*4 .. q*4+3
    float Ha[4], Hv[4];
    #pragma unroll
    for (int mi = 0; mi < 4; ++mi) {
        const int m = q * 4 + mi;
        float sa = 0.f, sv = 0.f;
        #pragma unroll
        for (int j = 0; j < 8; ++j) {
            sa = fmaf(ia[j], Wca[m * 8 + j], sa);
            sv = fmaf(va[j], Wcv[m * 8 + j], sv);
        }
        Ha[mi] = sa; Hv[mi] = sv;
    }
    for (int k4 = 0; k4 < 64; k4 += 4) {
        const f32x4 a4 = *(const f32x4*)(iv + k4);
        const f32x4 b4 = *(const f32x4*)(iv + 64 + k4);
        #pragma unroll
        for (int mi = 0; mi < 4; ++mi) {
            const int m = q * 4 + mi;
            const f32x4 wa = *(const f32x4*)(Wa + m * 64 + k4);
            const f32x4 wv = *(const f32x4*)(Wv + m * 64 + k4);
            #pragma unroll
            for (int j = 0; j < 4; ++j) {
                Ha[mi] = fmaf(a4[j], wa[j], Ha[mi]);
                Hv[mi] = fmaf(b4[j], wv[j], Hv[mi]);
            }
        }
    }
    #pragma unroll
    for (int mi = 0; mi < 4; ++mi) {
        Ha[mi] = fmaxf(ALPHA * Ha[mi], 0.f);
        Hv[mi] = fmaxf((1.f - ALPHA) * Hv[mi], 0.f);
    }

    __syncthreads();   // protect red reuse (step-3 reads done before step-7 writes)

    // step 7: ha/hv partials over this thread's m-range
    #pragma unroll
    for (int j = 0; j < 8; ++j) {
        float hap = 0.f, hvp = 0.f;
        #pragma unroll
        for (int mi = 0; mi < 4; ++mi) {
            hap = fmaf(Ha[mi], Wha[j * 32 + q * 4 + mi], hap);
            hvp = fmaf(Hv[mi], Whv[j * 32 + q * 4 + mi], hvp);
        }
        red[(q * 16 + j) * 64 + s] = hap;
        red[(q * 16 + 8 + j) * 64 + s] = hvp;
    }
    __syncthreads();
    float ha[8], hv[8];
    #pragma unroll
    for (int j = 0; j < 8; ++j) {
        float sa = 0.f, sv = 0.f;
        #pragma unroll
        for (int g = 0; g < 8; ++g) {
            sa += red[(g * 16 + j) * 64 + s];
            sv += red[(g * 16 + 8 + j) * 64 + s];
        }
        ha[j] = sa; hv[j] = sv;
    }

    // step 9: out = X[144] * G + c — this thread: o = q*4 .. q*4+3
    float o4[4];
    #pragma unroll
    for (int oi = 0; oi < 4; ++oi) o4[oi] = cvec[q * 4 + oi];
    for (int k4 = 0; k4 < 128; k4 += 4) {
        const f32x4 a4 = *(const f32x4*)(iv + k4);
        const f32x4 g0 = *(const f32x4*)(G + (k4 + 0) * 32 + q * 4);
        const f32x4 g1 = *(const f32x4*)(G + (k4 + 1) * 32 + q * 4);
        const f32x4 g2 = *(const f32x4*)(G + (k4 + 2) * 32 + q * 4);
        const f32x4 g3 = *(const f32x4*)(G + (k4 + 3) * 32 + q * 4);
        #pragma unroll
        for (int oi = 0; oi < 4; ++oi) {
            o4[oi] = fmaf(a4[0], g0[oi], o4[oi]);
            o4[oi] = fmaf(a4[1], g1[oi], o4[oi]);
            o4[oi] = fmaf(a4[2], g2[oi], o4[oi]);
            o4[oi] = fmaf(a4[3], g3[oi], o4[oi]);
        }
    }
    #pragma unroll
    for (int j = 0; j < 8; ++j) {
        const float aj = ALPHA * ha[j];
        const float vj = (1.f - ALPHA) * hv[j];
        const f32x4 gja = *(const f32x4*)(G + (128 + j) * 32 + q * 4);
        const f32x4 gjv = *(const f32x4*)(G + (136 + j) * 32 + q * 4);
        #pragma unroll
        for (int oi = 0; oi < 4; ++oi) {
            o4[oi] = fmaf(aj, gja[oi], o4[oi]);
            o4[oi] = fmaf(vj, gjv[oi], o4[oi]);
        }
    }
    f32x4 ov = {o4[0], o4[1], o4[2], o4[3]};
    *(f32x4*)(out + (size_t)(s0 + s) * 32 + q * 4) = ov;
}

extern "C" void kernel_launch(void* const* d_in, const int* in_sizes, int n_in,
                              void* d_out, int out_size, void* d_ws, size_t ws_size,
                              hipStream_t stream) {
    const float* f1    = (const float*)d_in[0];
    const float* f2    = (const float*)d_in[1];
    const float* We1   = (const float*)d_in[2];
    const float* be1   = (const float*)d_in[3];
    const float* We2   = (const float*)d_in[4];
    const float* be2   = (const float*)d_in[5];
    const float* Waffa = (const float*)d_in[6];
    const float* Waffv = (const float*)d_in[7];
    const float* Wa    = (const float*)d_in[8];
    const float* Wv    = (const float*)d_in[9];
    const float* Wca   = (const float*)d_in[10];
    const float* Wcv   = (const float*)d_in[11];
    const float* Wha   = (const float*)d_in[12];
    const float* Whv   = (const float*)d_in[13];
    const float* Wr1   = (const float*)d_in[14];
    const float* br1   = (const float*)d_in[15];
    const float* Wr2   = (const float*)d_in[16];
    const float* br2   = (const float*)d_in[17];
    float* outp = (float*)d_out;

    const int Btot = in_sizes[0] / 768;

    // d_ws layout (bytes): M[0,73728) G[73728,92160) c[92160,92288)
    //                      Wb1[92288,190592) Wb2[190592,272512)
    float* M = (float*)d_ws;
    float* G = (float*)((char*)d_ws + 73728);
    float* c = (float*)((char*)d_ws + 92160);
    unsigned short* Wb1 = (unsigned short*)((char*)d_ws + 92288);
    unsigned short* Wb2 = (unsigned short*)((char*)d_ws + 190592);

    prepA<<<(144 * 128 + 255) / 256, 256, 0, stream>>>(Wr1, M);
    prepB<<<(144 * 32 + 32 + 255) / 256, 256, 0, stream>>>(M, Wr2, br1, br2, G, c);
    prepW<<<(64 * 768 + 255) / 256, 256, 0, stream>>>(We1, We2, Wb1, Wb2);
    mica_main<<<Btot / SPB, 512, 0, stream>>>(f1, f2, Wb1, Wb2, be1, be2,
                                              Waffa, Waffv, Wa, Wv, Wca, Wcv, Wha, Whv,
                                              G, c, outp);
}

// Round 3
// 86.181 us; speedup vs baseline: 2.0757x; 1.1413x over previous
//
#include <hip/hip_runtime.h>
#include <hip/hip_bf16.h>

#define ALPHA 0.8f
#define SPB 64      // samples per block
#define IVW 132     // imu/vis LDS row stride (float4-aligned)

typedef __attribute__((ext_vector_type(8))) short bf16x8;
typedef __attribute__((ext_vector_type(8))) unsigned short ushort8;
typedef __attribute__((ext_vector_type(4))) float f32x4;

__device__ __host__ __forceinline__ unsigned short bfu(float x) {
    __hip_bfloat16 h = __float2bfloat16(x);   // RNE
    return __builtin_bit_cast(unsigned short, h);
}

// ---------------- prep kernels ----------------
// collapse r1+r2 into G[144][32], c[32]  (verified R0/R1)
__global__ void prepA(const float* __restrict__ Wr1, float* __restrict__ M) {
    int idx = blockIdx.x * 256 + threadIdx.x;
    if (idx >= 144 * 128) return;
    int x = idx >> 7;
    int r = idx & 127;
    const float* row = Wr1 + (size_t)r * 1024;
    float s = 0.f;
    if (x < 64) {
        #pragma unroll
        for (int j = 0; j < 8; ++j) s += row[j * 128 + x];
    } else if (x < 128) {
        #pragma unroll
        for (int j = 0; j < 8; ++j) s += row[j * 128 + 64 + (x - 64)];
    } else if (x < 136) {
        int j = x - 128;
        for (int k = 0; k < 64; ++k) s += row[j * 128 + k];
    } else {
        int j = x - 136;
        for (int k = 0; k < 64; ++k) s += row[j * 128 + 64 + k];
    }
    M[x * 128 + r] = s;
}

__global__ void prepB(const float* __restrict__ M, const float* __restrict__ Wr2,
                      const float* __restrict__ br1, const float* __restrict__ br2,
                      float* __restrict__ G, float* __restrict__ c) {
    int idx = blockIdx.x * 256 + threadIdx.x;
    if (idx < 144 * 32) {
        int x = idx >> 5, o = idx & 31;
        const float* m = M + x * 128;
        const float* w = Wr2 + o * 128;
        float s = 0.f;
        for (int r = 0; r < 128; ++r) s = fmaf(m[r], w[r], s);
        G[x * 32 + o] = s;
    } else if (idx < 144 * 32 + 32) {
        int o = idx - 144 * 32;
        const float* w = Wr2 + o * 128;
        float s = br2[o];
        for (int r = 0; r < 128; ++r) s = fmaf(br1[r], w[r], s);
        c[o] = s;
    }
}

// convert encoder weights to bf16; enc2 padded [64][640] with zeros past k=600
__global__ void prepW(const float* __restrict__ We1, const float* __restrict__ We2,
                      unsigned short* __restrict__ Wb1, unsigned short* __restrict__ Wb2) {
    int i = blockIdx.x * 256 + threadIdx.x;
    if (i < 64 * 768) Wb1[i] = bfu(We1[i]);
    if (i < 64 * 640) {
        int r = i / 640, k = i - r * 640;
        Wb2[i] = (k < 600) ? bfu(We2[r * 600 + k]) : (unsigned short)0;
    }
}

// ---------------- main kernel: 256 threads = 4 waves, 64 samples/block ----------------
// Wave w owns samples w*16..w*16+15 and ALL 64 outputs (4 accs).
// W quarter [64 n][KQ k] staged in LDS (XOR-chunk swizzle); A-frags straight
// from global to registers (lane-contiguous 8 floats) -> no inner-loop barriers.
template <int ROWLEN, int KPAD, int KQ, int NCH>
__device__ __forceinline__ void encMF(const float* __restrict__ X,
                                      const unsigned short* __restrict__ Wb,
                                      const float* __restrict__ bias,
                                      short* sW, float* sIV,
                                      int colbase, int s0, int t) {
    const int w = t >> 6, l = t & 63;
    const int r16 = l & 15, kg = l >> 4;
    const float* xrow = X + (size_t)(s0 + w * 16 + r16) * ROWLEN;

    const int srow = t >> 2;          // staging: row 0..63
    const int sc0 = (t & 3) * 6;      // staging: 6 chunks per thread

    f32x4 acc0 = {0.f,0.f,0.f,0.f}, acc1 = {0.f,0.f,0.f,0.f};
    f32x4 acc2 = {0.f,0.f,0.f,0.f}, acc3 = {0.f,0.f,0.f,0.f};

    #pragma unroll
    for (int kq = 0; kq < 4; ++kq) {
        __syncthreads();   // prev quarter's sW reads done
        const unsigned short* wsrc = Wb + srow * KPAD + kq * KQ;
        #pragma unroll
        for (int j = 0; j < 6; ++j) {
            const int c = sc0 + j;
            const int phys = (c & 24) | ((c & 7) ^ (srow & 7));
            ushort8 v;
            if (KQ == 192 || c < (KQ / 8)) {
                v = *(const ushort8*)(wsrc + c * 8);
            } else {
                #pragma unroll
                for (int e = 0; e < 8; ++e) v[e] = 0;
            }
            *(ushort8*)((char*)sW + srow * 384 + phys * 16) = v;
        }
        __syncthreads();

        #pragma unroll
        for (int kk = 0; kk < NCH; ++kk) {
            const int kb = kq * KQ + kk * 32 + kg * 8;   // lane's global k base
            ushort8 pa;
            #pragma unroll
            for (int e = 0; e < 8; ++e) pa[e] = 0;
            if (ROWLEN == KPAD || kb < ROWLEN) {
                const float4 u = *(const float4*)(xrow + kb);
                const float4 v2 = *(const float4*)(xrow + kb + 4);
                pa[0] = bfu(u.x); pa[1] = bfu(u.y); pa[2] = bfu(u.z); pa[3] = bfu(u.w);
                pa[4] = bfu(v2.x); pa[5] = bfu(v2.y); pa[6] = bfu(v2.z); pa[7] = bfu(v2.w);
            }
            const bf16x8 af = __builtin_bit_cast(bf16x8, pa);
            const int c = kk * 4 + kg;
            const int c24 = c & 24, c7 = c & 7;
            {
                const int n = r16;
                const bf16x8 bf = *(const bf16x8*)((const char*)sW + n * 384 + (c24 | (c7 ^ (n & 7))) * 16);
                acc0 = __builtin_amdgcn_mfma_f32_16x16x32_bf16(af, bf, acc0, 0, 0, 0);
            }
            {
                const int n = 16 + r16;
                const bf16x8 bf = *(const bf16x8*)((const char*)sW + n * 384 + (c24 | (c7 ^ (n & 7))) * 16);
                acc1 = __builtin_amdgcn_mfma_f32_16x16x32_bf16(af, bf, acc1, 0, 0, 0);
            }
            {
                const int n = 32 + r16;
                const bf16x8 bf = *(const bf16x8*)((const char*)sW + n * 384 + (c24 | (c7 ^ (n & 7))) * 16);
                acc2 = __builtin_amdgcn_mfma_f32_16x16x32_bf16(af, bf, acc2, 0, 0, 0);
            }
            {
                const int n = 48 + r16;
                const bf16x8 bf = *(const bf16x8*)((const char*)sW + n * 384 + (c24 | (c7 ^ (n & 7))) * 16);
                acc3 = __builtin_amdgcn_mfma_f32_16x16x32_bf16(af, bf, acc3, 0, 0, 0);
            }
        }
    }
    // C/D: col = lane&15 (=n offset), row = 4*(lane>>4)+reg (=sample offset)
    const int rr = 4 * kg;
    #pragma unroll
    for (int reg = 0; reg < 4; ++reg) {
        const int row = w * 16 + rr + reg;
        sIV[row * IVW + colbase +  0 + r16] = acc0[reg] + bias[ 0 + r16];
        sIV[row * IVW + colbase + 16 + r16] = acc1[reg] + bias[16 + r16];
        sIV[row * IVW + colbase + 32 + r16] = acc2[reg] + bias[32 + r16];
        sIV[row * IVW + colbase + 48 + r16] = acc3[reg] + bias[48 + r16];
    }
}

__global__ __launch_bounds__(256, 2)
void mica_main(const float* __restrict__ f1, const float* __restrict__ f2,
               const unsigned short* __restrict__ Wb1, const unsigned short* __restrict__ Wb2,
               const float* __restrict__ be1, const float* __restrict__ be2,
               const float* __restrict__ Waffa, const float* __restrict__ Waffv,
               const float* __restrict__ Wa, const float* __restrict__ Wv,
               const float* __restrict__ Wca, const float* __restrict__ Wcv,
               const float* __restrict__ Wha, const float* __restrict__ Whv,
               const float* __restrict__ G, const float* __restrict__ cvec,
               float* __restrict__ out) {
    __shared__ float sIV[SPB * IVW];     // 33.8 KB  [64 samples][imu(64)|vis(64)]
    __shared__ float scratch[6144];      // 24 KB: W quarter tile / tail reduction buf
    short* sW = (short*)scratch;
    const int t = threadIdx.x;
    const int s0 = blockIdx.x * SPB;

    // ---- phase 1: MFMA encoders into sIV ----
    encMF<768, 768, 192, 6>(f1, Wb1, be1, sW, sIV, 0, s0, t);
    encMF<600, 640, 160, 5>(f2, Wb2, be2, sW, sIV, 64, s0, t);
    __syncthreads();

    // ---- phase 2: per-sample tail; s = sample, q = wave (0..3) ----
    const int s = t & 63;
    const int q = t >> 6;
    const float* iv = sIV + s * IVW;
    float* red = scratch;

    // step 3: moments Sii, Siv, Svv (4-way split over k, 16 k each)
    float sii = 0.f, siv = 0.f, svv = 0.f;
    #pragma unroll
    for (int h = 0; h < 2; ++h) {
        const f32x4 a0 = *(const f32x4*)(iv + q * 16 + h * 8);
        const f32x4 a1 = *(const f32x4*)(iv + q * 16 + h * 8 + 4);
        const f32x4 b0 = *(const f32x4*)(iv + 64 + q * 16 + h * 8);
        const f32x4 b1 = *(const f32x4*)(iv + 64 + q * 16 + h * 8 + 4);
        #pragma unroll
        for (int j = 0; j < 4; ++j) {
            sii = fmaf(a0[j], a0[j], sii); siv = fmaf(a0[j], b0[j], siv); svv = fmaf(b0[j], b0[j], svv);
            sii = fmaf(a1[j], a1[j], sii); siv = fmaf(a1[j], b1[j], siv); svv = fmaf(b1[j], b1[j], svv);
        }
    }
    red[(q * 3 + 0) * 64 + s] = sii;
    red[(q * 3 + 1) * 64 + s] = siv;
    red[(q * 3 + 2) * 64 + s] = svv;
    __syncthreads();
    sii = 0.f; siv = 0.f; svv = 0.f;
    #pragma unroll
    for (int g = 0; g < 4; ++g) {
        sii += red[(g * 3 + 0) * 64 + s];
        siv += red[(g * 3 + 1) * 64 + s];
        svv += red[(g * 3 + 2) * 64 + s];
    }

    // step 4: attention gates (scale = 1/8)
    float ia[8], va[8];
    #pragma unroll
    for (int j = 0; j < 8; ++j) {
        ia[j] = tanhf((sii * Waffa[j * 2 + 0] + siv * Waffa[j * 2 + 1]) * 0.125f);
        va[j] = tanhf((siv * Waffv[j * 2 + 0] + svv * Waffv[j * 2 + 1]) * 0.125f);
    }

    // steps 5-6: H_a, H_v — this thread owns m = q*8 .. q*8+7
    float Ha[8], Hv[8];
    #pragma unroll
    for (int mi = 0; mi < 8; ++mi) {
        const int m = q * 8 + mi;
        float sa = 0.f, sv = 0.f;
        #pragma unroll
        for (int j = 0; j < 8; ++j) {
            sa = fmaf(ia[j], Wca[m * 8 + j], sa);
            sv = fmaf(va[j], Wcv[m * 8 + j], sv);
        }
        Ha[mi] = sa; Hv[mi] = sv;
    }
    for (int k4 = 0; k4 < 64; k4 += 4) {
        const f32x4 a4 = *(const f32x4*)(iv + k4);
        const f32x4 b4 = *(const f32x4*)(iv + 64 + k4);
        #pragma unroll
        for (int mi = 0; mi < 8; ++mi) {
            const int m = q * 8 + mi;
            const f32x4 wa = *(const f32x4*)(Wa + m * 64 + k4);
            const f32x4 wv = *(const f32x4*)(Wv + m * 64 + k4);
            #pragma unroll
            for (int j = 0; j < 4; ++j) {
                Ha[mi] = fmaf(a4[j], wa[j], Ha[mi]);
                Hv[mi] = fmaf(b4[j], wv[j], Hv[mi]);
            }
        }
    }
    #pragma unroll
    for (int mi = 0; mi < 8; ++mi) {
        Ha[mi] = fmaxf(ALPHA * Ha[mi], 0.f);
        Hv[mi] = fmaxf((1.f - ALPHA) * Hv[mi], 0.f);
    }

    __syncthreads();   // step-3 reads of red done before step-7 writes

    // step 7: ha/hv partials over this thread's m-range (8 m each)
    #pragma unroll
    for (int j = 0; j < 8; ++j) {
        float hap = 0.f, hvp = 0.f;
        #pragma unroll
        for (int mi = 0; mi < 8; ++mi) {
            hap = fmaf(Ha[mi], Wha[j * 32 + q * 8 + mi], hap);
            hvp = fmaf(Hv[mi], Whv[j * 32 + q * 8 + mi], hvp);
        }
        red[(q * 16 + j) * 64 + s] = hap;
        red[(q * 16 + 8 + j) * 64 + s] = hvp;
    }
    __syncthreads();
    float ha[8], hv[8];
    #pragma unroll
    for (int j = 0; j < 8; ++j) {
        float sa = 0.f, sv = 0.f;
        #pragma unroll
        for (int g = 0; g < 4; ++g) {
            sa += red[(g * 16 + j) * 64 + s];
            sv += red[(g * 16 + 8 + j) * 64 + s];
        }
        ha[j] = sa; hv[j] = sv;
    }

    // step 9: out = X[144] * G + c — this thread: o = q*8 .. q*8+7
    float o8[8];
    #pragma unroll
    for (int oi = 0; oi < 8; ++oi) o8[oi] = cvec[q * 8 + oi];
    for (int k4 = 0; k4 < 128; k4 += 4) {
        const f32x4 a4 = *(const f32x4*)(iv + k4);
        #pragma unroll
        for (int kk = 0; kk < 4; ++kk) {
            const f32x4 g0 = *(const f32x4*)(G + (k4 + kk) * 32 + q * 8);
            const f32x4 g1 = *(const f32x4*)(G + (k4 + kk) * 32 + q * 8 + 4);
            #pragma unroll
            for (int oi = 0; oi < 4; ++oi) {
                o8[oi]     = fmaf(a4[kk], g0[oi], o8[oi]);
                o8[4 + oi] = fmaf(a4[kk], g1[oi], o8[4 + oi]);
            }
        }
    }
    #pragma unroll
    for (int j = 0; j < 8; ++j) {
        const float aj = ALPHA * ha[j];
        const float vj = (1.f - ALPHA) * hv[j];
        const f32x4 ga0 = *(const f32x4*)(G + (128 + j) * 32 + q * 8);
        const f32x4 ga1 = *(const f32x4*)(G + (128 + j) * 32 + q * 8 + 4);
        const f32x4 gv0 = *(const f32x4*)(G + (136 + j) * 32 + q * 8);
        const f32x4 gv1 = *(const f32x4*)(G + (136 + j) * 32 + q * 8 + 4);
        #pragma unroll
        for (int oi = 0; oi < 4; ++oi) {
            o8[oi]     = fmaf(aj, ga0[oi], o8[oi]);
            o8[4 + oi] = fmaf(aj, ga1[oi], o8[4 + oi]);
            o8[oi]     = fmaf(vj, gv0[oi], o8[oi]);
            o8[4 + oi] = fmaf(vj, gv1[oi], o8[4 + oi]);
        }
    }
    f32x4 v0 = {o8[0], o8[1], o8[2], o8[3]};
    f32x4 v1 = {o8[4], o8[5], o8[6], o8[7]};
    float* op = out + (size_t)(s0 + s) * 32 + q * 8;
    *(f32x4*)op = v0;
    *((f32x4*)op + 1) = v1;
}

extern "C" void kernel_launch(void* const* d_in, const int* in_sizes, int n_in,
                              void* d_out, int out_size, void* d_ws, size_t ws_size,
                              hipStream_t stream) {
    const float* f1    = (const float*)d_in[0];
    const float* f2    = (const float*)d_in[1];
    const float* We1   = (const float*)d_in[2];
    const float* be1   = (const float*)d_in[3];
    const float* We2   = (const float*)d_in[4];
    const float* be2   = (const float*)d_in[5];
    const float* Waffa = (const float*)d_in[6];
    const float* Waffv = (const float*)d_in[7];
    const float* Wa    = (const float*)d_in[8];
    const float* Wv    = (const float*)d_in[9];
    const float* Wca   = (const float*)d_in[10];
    const float* Wcv   = (const float*)d_in[11];
    const float* Wha   = (const float*)d_in[12];
    const float* Whv   = (const float*)d_in[13];
    const float* Wr1   = (const float*)d_in[14];
    const float* br1   = (const float*)d_in[15];
    const float* Wr2   = (const float*)d_in[16];
    const float* br2   = (const float*)d_in[17];
    float* outp = (float*)d_out;

    const int Btot = in_sizes[0] / 768;

    // d_ws layout (bytes): M[0,73728) G[73728,92160) c[92160,92288)
    //                      Wb1[92288,190592) Wb2[190592,272512)
    float* M = (float*)d_ws;
    float* G = (float*)((char*)d_ws + 73728);
    float* c = (float*)((char*)d_ws + 92160);
    unsigned short* Wb1 = (unsigned short*)((char*)d_ws + 92288);
    unsigned short* Wb2 = (unsigned short*)((char*)d_ws + 190592);

    prepA<<<(144 * 128 + 255) / 256, 256, 0, stream>>>(Wr1, M);
    prepB<<<(144 * 32 + 32 + 255) / 256, 256, 0, stream>>>(M, Wr2, br1, br2, G, c);
    prepW<<<(64 * 768 + 255) / 256, 256, 0, stream>>>(We1, We2, Wb1, Wb2);
    mica_main<<<Btot / SPB, 256, 0, stream>>>(f1, f2, Wb1, Wb2, be1, be2,
                                              Waffa, Waffv, Wa, Wv, Wca, Wcv, Wha, Whv,
                                              G, c, outp);
}